// Round 2
// baseline (3984.203 us; speedup 1.0000x reference)
//
#include <hip/hip_runtime.h>

// Persistent cooperative seq2seq GRU: B=1024, H=1024, IN=55(pad 64), 49 enc + 25 dec.
// Grid = 256 blocks (1/CU, co-resident) x 512 threads. Weights LDS-resident.
// ws: x_enc 6.42MB | fc_bf 128KB | hA0/hA1 2x2MB | inA0/inA1 2x128KB | counter.

typedef unsigned short ushort_t;
typedef __bf16 bf16x8 __attribute__((ext_vector_type(8)));
typedef float f32x4 __attribute__((ext_vector_type(4)));

#define NBLK 256
#define NTHR 512
#define MFMA(a, b, c) __builtin_amdgcn_mfma_f32_16x16x32_bf16(a, b, c, 0, 0, 0)

__device__ __forceinline__ ushort_t f2bf(float f) {
  union { float f; unsigned u; } x; x.f = f;
  unsigned r = x.u + 0x7fffu + ((x.u >> 16) & 1u);
  return (ushort_t)(r >> 16);
}
__device__ __forceinline__ float sigmf(float x) { return 1.f / (1.f + __expf(-x)); }
__device__ __forceinline__ float tanhf_(float x) { return 1.f - 2.f / (__expf(2.f * x) + 1.f); }

__device__ __forceinline__ void gl_lds16(const ushort_t* g, ushort_t* l) {
  __builtin_amdgcn_global_load_lds(
      (const __attribute__((address_space(1))) void*)g,
      (__attribute__((address_space(3))) void*)l, 16, 0, 0);
}

__global__ __launch_bounds__(NTHR, 2)
void seq2seq_persist(const float* __restrict__ enc, const float* __restrict__ dec,
                     const float* __restrict__ Wih, const float* __restrict__ Whh,
                     const float* __restrict__ b_ih, const float* __restrict__ b_hh,
                     const float* __restrict__ fcw, const float* __restrict__ fcb,
                     float* __restrict__ outp,
                     ushort_t* __restrict__ x_enc, ushort_t* __restrict__ fc_bf,
                     ushort_t* hA0, ushort_t* hA1,
                     ushort_t* inA0, ushort_t* inA1,
                     unsigned* cnt) {
  // LDS: Wh 99072B + Wi 6912B + Ab 32768B = 138752B -> 1 block/CU.
  __shared__ ushort_t Wh[3 * 16 * 1032];  // [gate][jcol 16][K 1024 pad 1032]
  __shared__ ushort_t Wi[3 * 16 * 72];    // [gate][jcol 16][K 64 pad 72]
  __shared__ ushort_t Ab[2][8192];        // A-tile dbuf: 256 rows x 32 K (chunk-swizzled)

  const int tid = threadIdx.x;
  const int b = blockIdx.x;
  const int jt = b & 63, mt = b >> 6;
  const int m0 = mt << 8, j0 = jt << 4;
  const int w = tid >> 6, l = tid & 63;
  const int fr = l & 15, fq4 = l >> 4;

  // ---- init phase A: grid-strided global conversions ----
  for (int i = b * NTHR + tid; i < 4390912; i += NBLK * NTHR) {
    if (i < 3211264) {  // x_enc[t][row][64]
      int t = i >> 16, row = (i >> 6) & 1023, k = i & 63;
      x_enc[i] = (k < 55) ? f2bf(enc[(row * 50 + t) * 55 + k]) : (ushort_t)0;
    } else if (i < 3276800) {  // fc_bf[col 64][K 1024]
      int j = i - 3211264; int col = j >> 10, k = j & 1023;
      fc_bf[j] = (col < 55) ? f2bf(fcw[col * 1024 + k]) : (ushort_t)0;
    } else if (i < 3342336) {  // inA0[row][64] = dec[:,0,:]
      int j = i - 3276800; int row = j >> 6, k = j & 63;
      inA0[j] = (k < 55) ? f2bf(dec[row * 1375 + k]) : (ushort_t)0;
    } else {  // hA0 zero
      hA0[i - 3342336] = 0;
    }
  }
  // ---- init phase B: block-local LDS weights (fp32 global -> bf16 LDS) ----
  for (int i = tid; i < 49152; i += NTHR) {
    int g = i >> 14, r = (i >> 10) & 15, k = i & 1023;
    Wh[(g * 16 + r) * 1032 + k] = f2bf(Whh[(g * 1024 + j0 + r) * 1024 + k]);
  }
  for (int i = tid; i < 3072; i += NTHR) {
    int g = i >> 10, r = (i >> 6) & 15, k = i & 63;
    Wi[(g * 16 + r) * 72 + k] = (k < 55) ? f2bf(Wih[(g * 1024 + j0 + r) * 55 + k]) : (ushort_t)0;
  }

  // Per-thread bias constants for this block's 16 cols.
  const int jc = j0 + fr;
  const float brz = b_ih[jc] + b_hh[jc];
  const float bzz = b_ih[1024 + jc] + b_hh[1024 + jc];
  const float bin = b_ih[2048 + jc];
  const float bhn = b_hh[2048 + jc];

  // Decoder-output blocks (jt<4) hold running inp in regs.
  const bool isdec = (jt < 4);
  const int jcD = j0 + fr;  // 0..63 for dec blocks
  float inp[2][4];
  float fcbr = 0.f;
  if (isdec) {
    fcbr = (jcD < 55) ? fcb[jcD] : 0.f;
#pragma unroll
    for (int mi = 0; mi < 2; ++mi)
#pragma unroll
      for (int v = 0; v < 4; ++v) {
        int bR = m0 + w * 32 + mi * 16 + fq4 * 4 + v;
        inp[mi][v] = (jcD < 55) ? dec[bR * 1375 + jcD] : 0.f;
      }
  }

  float hreg[2][4] = {{0.f, 0.f, 0.f, 0.f}, {0.f, 0.f, 0.f, 0.f}};

  ushort_t* hAbuf[2] = {hA0, hA1};
  ushort_t* inbuf[2] = {inA0, inA1};
  int p = 0, q = 0;

  unsigned phase = 0;
  auto gsync = [&]() {
    __syncthreads();
    if (tid == 0) {
      __threadfence();
      atomicAdd(cnt, 1u);
      ++phase;
      while (__hip_atomic_load(cnt, __ATOMIC_RELAXED, __HIP_MEMORY_SCOPE_AGENT) <
             phase * (unsigned)NBLK)
        __builtin_amdgcn_s_sleep(2);
      __threadfence();
    }
    __syncthreads();
  };

  const ushort_t* Asrc = hA0;
  const ushort_t* Xsrc = x_enc;
  // Stage one 256x32 A-tile (16KB) via global_load_lds; chunk-XOR-swizzled so
  // frag ds_read_b128 is 2-way-conflict-free. Dest must be lane-contiguous.
  auto stageA = [&](int kt, int bsel) {
#pragma unroll
    for (int c = 0; c < 2; ++c) {
      int L = (w * 2 + c) * 64 + l;
      int row = L >> 2;
      int jch = (L & 3) ^ ((row >> 1) & 3);
      const ushort_t* src = (kt < 32)
          ? Asrc + (m0 + row) * 1024 + kt * 32 + jch * 8
          : Xsrc + (m0 + row) * 64 + (kt - 32) * 32 + jch * 8;
      gl_lds16(src, &Ab[bsel][(w * 2 + c) * 512]);
    }
  };
  auto loadA = [&](const ushort_t* ab, int mi) {
    int row = w * 32 + mi * 16 + fr;
    int pos = fq4 ^ ((row >> 1) & 3);
    return *(const bf16x8*)(ab + row * 32 + pos * 8);
  };

  gsync();  // publish init

  for (int t = 0; t < 74; ++t) {
    Asrc = hAbuf[p];
    Xsrc = (t < 49) ? x_enc + t * 65536 : inbuf[q];

    f32x4 aR[2], aZ[2], aNH[2], aNX[2];
#pragma unroll
    for (int mi = 0; mi < 2; ++mi) {
      aR[mi] = (f32x4){0.f, 0.f, 0.f, 0.f};
      aZ[mi] = (f32x4){0.f, 0.f, 0.f, 0.f};
      aNH[mi] = (f32x4){0.f, 0.f, 0.f, 0.f};
      aNX[mi] = (f32x4){0.f, 0.f, 0.f, 0.f};
    }

    stageA(0, 0);
    __syncthreads();
#pragma unroll 2
    for (int kt = 0; kt < 34; ++kt) {
      if (kt < 33) stageA(kt + 1, (kt + 1) & 1);
      const ushort_t* ab = Ab[kt & 1];
      bf16x8 a0 = loadA(ab, 0);
      bf16x8 a1 = loadA(ab, 1);
      const ushort_t* bw;
      int gs;
      if (kt < 32) { bw = Wh + fr * 1032 + kt * 32 + fq4 * 8; gs = 1032; }
      else         { bw = Wi + fr * 72 + (kt - 32) * 32 + fq4 * 8; gs = 72; }
      bf16x8 br = *(const bf16x8*)(bw);
      bf16x8 bz = *(const bf16x8*)(bw + 16 * gs);
      bf16x8 bn = *(const bf16x8*)(bw + 32 * gs);
      aR[0] = MFMA(a0, br, aR[0]); aR[1] = MFMA(a1, br, aR[1]);
      aZ[0] = MFMA(a0, bz, aZ[0]); aZ[1] = MFMA(a1, bz, aZ[1]);
      if (kt < 32) { aNH[0] = MFMA(a0, bn, aNH[0]); aNH[1] = MFMA(a1, bn, aNH[1]); }
      else         { aNX[0] = MFMA(a0, bn, aNX[0]); aNX[1] = MFMA(a1, bn, aNX[1]); }
      __syncthreads();
    }

    // Epilogue: gates, fp32 h carry in regs, publish bf16 h.
    ushort_t* hAn = hAbuf[p ^ 1];
#pragma unroll
    for (int mi = 0; mi < 2; ++mi)
#pragma unroll
      for (int v = 0; v < 4; ++v) {
        float r = sigmf(aR[mi][v] + brz);
        float z = sigmf(aZ[mi][v] + bzz);
        float n = tanhf_(aNX[mi][v] + bin + r * (aNH[mi][v] + bhn));
        float h = (1.f - z) * n + z * hreg[mi][v];
        hreg[mi][v] = h;
        int bR = m0 + w * 32 + mi * 16 + fq4 * 4 + v;
        hAn[bR * 1024 + jc] = f2bf(h);
      }
    p ^= 1;
    gsync();

    if (t >= 49) {
      if (isdec) {
        // out(t) = inp + h_new @ fc^T + fc_b ; 16 blocks (jt<4), M=256,N=16,K=1024.
        Asrc = hAbuf[p];
        f32x4 fa[2] = {{0.f, 0.f, 0.f, 0.f}, {0.f, 0.f, 0.f, 0.f}};
        const ushort_t* fcp = fc_bf + jcD * 1024 + fq4 * 8;
        bf16x8 fbn = *(const bf16x8*)(fcp);
        stageA(0, 0);
        __syncthreads();
        for (int kt = 0; kt < 32; ++kt) {
          if (kt < 31) stageA(kt + 1, (kt + 1) & 1);
          bf16x8 fb = fbn;
          if (kt < 31) fbn = *(const bf16x8*)(fcp + (kt + 1) * 32);
          const ushort_t* ab = Ab[kt & 1];
          bf16x8 a0 = loadA(ab, 0);
          bf16x8 a1 = loadA(ab, 1);
          fa[0] = MFMA(a0, fb, fa[0]);
          fa[1] = MFMA(a1, fb, fa[1]);
          __syncthreads();
        }
        int td = t - 49;
        ushort_t* inn = inbuf[q ^ 1];
#pragma unroll
        for (int mi = 0; mi < 2; ++mi)
#pragma unroll
          for (int v = 0; v < 4; ++v) {
            int bR = m0 + w * 32 + mi * 16 + fq4 * 4 + v;
            float o = fa[mi][v] + inp[mi][v] + fcbr;
            inp[mi][v] = o;
            inn[bR * 64 + jcD] = f2bf(o);
            if (jcD < 55) outp[bR * 1375 + td * 55 + jcD] = o;
          }
      }
      q ^= 1;
      gsync();
    }
  }
}

extern "C" void kernel_launch(void* const* d_in, const int* in_sizes, int n_in,
                              void* d_out, int out_size, void* d_ws, size_t ws_size,
                              hipStream_t stream) {
  const float* enc  = (const float*)d_in[0];
  const float* dec  = (const float*)d_in[1];
  const float* Wih  = (const float*)d_in[2];
  const float* Whh  = (const float*)d_in[3];
  const float* b_ih = (const float*)d_in[4];
  const float* b_hh = (const float*)d_in[5];
  const float* fcw  = (const float*)d_in[6];
  const float* fcb  = (const float*)d_in[7];
  float* out = (float*)d_out;

  char* ws = (char*)d_ws;
  ushort_t* x_enc = (ushort_t*)ws; ws += (size_t)3211264 * 2;
  ushort_t* fc_bf = (ushort_t*)ws; ws += (size_t)65536 * 2;
  ushort_t* hA0   = (ushort_t*)ws; ws += (size_t)1048576 * 2;
  ushort_t* hA1   = (ushort_t*)ws; ws += (size_t)1048576 * 2;
  ushort_t* inA0  = (ushort_t*)ws; ws += (size_t)65536 * 2;
  ushort_t* inA1  = (ushort_t*)ws; ws += (size_t)65536 * 2;
  unsigned* cnt   = (unsigned*)ws; ws += 256;

  hipMemsetAsync(cnt, 0, 256, stream);
  seq2seq_persist<<<NBLK, NTHR, 0, stream>>>(
      enc, dec, Wih, Whh, b_ih, b_hh, fcw, fcb, out,
      x_enc, fc_bf, hA0, hA1, inA0, inA1, cnt);
}

// Round 3
// 3293.366 us; speedup vs baseline: 1.2098x; 1.2098x over previous
//
#include <hip/hip_runtime.h>

// Persistent cooperative seq2seq GRU, round 3.
// B=1024, H=1024, IN=55(pad64), 49 enc + 25 dec steps.
// 256 blocks x 512 thr (1 block/CU). Weights LDS-resident in MFMA fragment
// order (conflict-free). h kept in global in fragment order -> A-frags load
// straight to VGPRs (no LDS staging, no K-loop barriers). Per-mt 64-block
// group barriers (mt pinned to XCD pair via blockIdx&3).
//
// ws: cnt 4096B | x_enc 49*65536 ush | hA0,hA1 1048576 ush each |
//     in0,in1 65536 ush each.

typedef unsigned short ushort_t;
typedef __bf16 bf16x8 __attribute__((ext_vector_type(8)));
typedef float f32x4 __attribute__((ext_vector_type(4)));

#define MFMA(a, b, c) __builtin_amdgcn_mfma_f32_16x16x32_bf16(a, b, c, 0, 0, 0)

__device__ __forceinline__ ushort_t f2bf(float f) {
  union { float f; unsigned u; } x; x.f = f;
  unsigned r = x.u + 0x7fffu + ((x.u >> 16) & 1u);
  return (ushort_t)(r >> 16);
}
__device__ __forceinline__ float sigmf(float x) { return 1.f / (1.f + __expf(-x)); }
__device__ __forceinline__ float tanhf_(float x) { return 1.f - 2.f / (__expf(2.f * x) + 1.f); }
__device__ __forceinline__ bf16x8 ldg8(const ushort_t* p) { return *(const bf16x8*)p; }

__global__ __launch_bounds__(512, 2)
void seq2seq_persist(const float* __restrict__ enc, const float* __restrict__ dec,
                     const float* __restrict__ Wih, const float* __restrict__ Whh,
                     const float* __restrict__ b_ih, const float* __restrict__ b_hh,
                     const float* __restrict__ fcw, const float* __restrict__ fcb,
                     float* __restrict__ outp,
                     ushort_t* __restrict__ x_enc,
                     ushort_t* __restrict__ hA0, ushort_t* __restrict__ hA1,
                     ushort_t* __restrict__ in0, ushort_t* __restrict__ in1,
                     unsigned* cnt) {
  // LDS, all in MFMA-B fragment order [kc][col 16][8]: frag read = base+lane*16B.
  __shared__ ushort_t WhL[49152];  // 3 gates x 128 kc x 16 col x 8   (96 KB)
  __shared__ ushort_t WiL[3072];   // 3 gates x 8 kc x 16 col x 8     (6 KB)
  __shared__ ushort_t fcL[16384];  // 128 kc x 16 col x 8             (32 KB)

  const int tid = threadIdx.x;
  const int b = blockIdx.x;
  const int mt = b & 3;                              // XCD pair -> same m-tile
  const int jt = (b >> 3) + 32 * ((b & 7) >> 2);     // 0..63, unique per mt
  const int m0 = mt << 8, j0 = jt << 4;
  const int w = tid >> 6, l = tid & 63;
  const int fr = l & 15, fq4 = l >> 4;
  const int rowA = m0 + w * 32 + fr;                 // A-frag row, m-frag 0
  const bool isdec = (jt < 4);

  // ---------------- init: convert inputs/weights ----------------
  if (jt < 49) {  // x_enc[t=jt][kc][row][8] for this mt's rows
    const int t = jt;
    for (int i = tid; i < 2048; i += 512) {
      int kc = i >> 8, row = m0 + (i & 255);
      ushort_t* dst = x_enc + t * 65536 + (kc * 1024 + row) * 8;
      const float* src = enc + (row * 50 + t) * 55 + kc * 8;
#pragma unroll
      for (int j = 0; j < 8; ++j) {
        int k = kc * 8 + j;
        dst[j] = (k < 55) ? f2bf(src[j]) : (ushort_t)0;
      }
    }
  } else if (jt == 49) {  // in0[kc][row][8] = dec[:,0,:]
    for (int i = tid; i < 2048; i += 512) {
      int kc = i >> 8, row = m0 + (i & 255);
      ushort_t* dst = in0 + (kc * 1024 + row) * 8;
      const float* src = dec + row * 1375 + kc * 8;
#pragma unroll
      for (int j = 0; j < 8; ++j) {
        int k = kc * 8 + j;
        dst[j] = (k < 55) ? f2bf(src[j]) : (ushort_t)0;
      }
    }
  }
  for (int i = tid; i < 6144; i += 512) {  // WhL
    int g = i >> 11, c = (i >> 7) & 15, kc = i & 127;
    const float* src = Whh + (size_t)(g * 1024 + j0 + c) * 1024 + kc * 8;
    ushort_t* dst = WhL + ((g * 128 + kc) * 16 + c) * 8;
#pragma unroll
    for (int j = 0; j < 8; ++j) dst[j] = f2bf(src[j]);
  }
  for (int i = tid; i < 384; i += 512) {  // WiL
    int g = i >> 7, c = (i >> 3) & 15, kc = i & 7;
    const float* src = Wih + (size_t)(g * 1024 + j0 + c) * 55 + kc * 8;
    ushort_t* dst = WiL + ((g * 8 + kc) * 16 + c) * 8;
#pragma unroll
    for (int j = 0; j < 8; ++j) {
      int k = kc * 8 + j;
      dst[j] = (k < 55) ? f2bf(src[j]) : (ushort_t)0;
    }
  }
  if (isdec) {
    for (int i = tid; i < 2048; i += 512) {  // fcL; cols j0..j0+15 (<64)
      int kc = i >> 4, c = i & 15;
      int col = j0 + c;
      ushort_t* dst = fcL + (kc * 16 + c) * 8;
      const float* src = fcw + (size_t)col * 1024 + kc * 8;
#pragma unroll
      for (int j = 0; j < 8; ++j) dst[j] = (col < 55) ? f2bf(src[j]) : (ushort_t)0;
    }
  }

  // Per-thread constants
  const int jcB = j0 + fr;
  const float brz = b_ih[jcB] + b_hh[jcB];
  const float bzz = b_ih[1024 + jcB] + b_hh[1024 + jcB];
  const float bin = b_ih[2048 + jcB];
  const float bhn = b_hh[2048 + jcB];
  float fcbr = 0.f;
  float inp[2][4];
  if (isdec) {
    fcbr = (jcB < 55) ? fcb[jcB] : 0.f;
#pragma unroll
    for (int mi = 0; mi < 2; ++mi)
#pragma unroll
      for (int v = 0; v < 4; ++v) {
        int row = m0 + w * 32 + mi * 16 + fq4 * 4 + v;
        inp[mi][v] = (jcB < 55) ? dec[row * 1375 + jcB] : 0.f;
      }
  }
  float hreg[2][4] = {{0.f, 0.f, 0.f, 0.f}, {0.f, 0.f, 0.f, 0.f}};

  auto arrive_wait = [&](unsigned* c, unsigned tgt) {
    __syncthreads();
    if (tid == 0) {
      __threadfence();
      atomicAdd(c, 1u);
      while (__hip_atomic_load(c, __ATOMIC_RELAXED, __HIP_MEMORY_SCOPE_AGENT) < tgt)
        __builtin_amdgcn_s_sleep(2);
    }
    __syncthreads();
    __builtin_amdgcn_fence(__ATOMIC_ACQUIRE, "agent");
  };
  auto wait_only = [&](unsigned* c, unsigned tgt) {
    __syncthreads();
    if (tid == 0) {
      while (__hip_atomic_load(c, __ATOMIC_RELAXED, __HIP_MEMORY_SCOPE_AGENT) < tgt)
        __builtin_amdgcn_s_sleep(2);
    }
    __syncthreads();
    __builtin_amdgcn_fence(__ATOMIC_ACQUIRE, "agent");
  };

  arrive_wait(&cnt[mt], 64);  // publish init

  ushort_t* hbuf[2] = {hA0, hA1};
  ushort_t* inbuf[2] = {in0, in1};
  int p = 0;

  for (int t = 0; t < 74; ++t) {
    f32x4 aR[2], aZ[2], aNH[2], aNX[2];
#pragma unroll
    for (int mi = 0; mi < 2; ++mi) {
      aR[mi] = (f32x4){0.f, 0.f, 0.f, 0.f};
      aZ[mi] = (f32x4){0.f, 0.f, 0.f, 0.f};
      aNH[mi] = (f32x4){0.f, 0.f, 0.f, 0.f};
      aNX[mi] = (f32x4){0.f, 0.f, 0.f, 0.f};
    }

    if (t > 0) {  // h-part: 32 kt, A direct from global (frag order), B from LDS
      const ushort_t* abase = hbuf[p] + (fq4 * 1024 + rowA) * 8;
      bf16x8 a0 = ldg8(abase), a1 = ldg8(abase + 128);
      bf16x8 p0 = ldg8(abase + 32768), p1 = ldg8(abase + 32768 + 128);
#pragma unroll 2
      for (int kt = 0; kt < 32; ++kt) {
        int kp = (kt + 2 < 32) ? kt + 2 : 31;
        bf16x8 n0 = ldg8(abase + kp * 32768);
        bf16x8 n1 = ldg8(abase + kp * 32768 + 128);
        const ushort_t* bp = WhL + kt * 512 + l * 8;
        bf16x8 br = *(const bf16x8*)(bp);
        bf16x8 bz = *(const bf16x8*)(bp + 16384);
        bf16x8 bn = *(const bf16x8*)(bp + 32768);
        aR[0] = MFMA(a0, br, aR[0]);  aR[1] = MFMA(a1, br, aR[1]);
        aZ[0] = MFMA(a0, bz, aZ[0]);  aZ[1] = MFMA(a1, bz, aZ[1]);
        aNH[0] = MFMA(a0, bn, aNH[0]); aNH[1] = MFMA(a1, bn, aNH[1]);
        a0 = p0; a1 = p1; p0 = n0; p1 = n1;
      }
    }

    if (t >= 50) wait_only(&cnt[512 + (t - 49) * 4 + mt], 4);
    const ushort_t* Xs = (t < 49) ? x_enc + t * 65536 : inbuf[(t - 49) & 1];

    {  // x-part: 2 kt over the 64-wide input
      const ushort_t* xb = Xs + (fq4 * 1024 + rowA) * 8;
      bf16x8 xa[2][2];
      xa[0][0] = ldg8(xb);          xa[0][1] = ldg8(xb + 128);
      xa[1][0] = ldg8(xb + 32768);  xa[1][1] = ldg8(xb + 32768 + 128);
#pragma unroll
      for (int kx = 0; kx < 2; ++kx) {
        const ushort_t* bp = WiL + kx * 512 + l * 8;
        bf16x8 br = *(const bf16x8*)(bp);
        bf16x8 bz = *(const bf16x8*)(bp + 1024);
        bf16x8 bn = *(const bf16x8*)(bp + 2048);
        aR[0] = MFMA(xa[kx][0], br, aR[0]);  aR[1] = MFMA(xa[kx][1], br, aR[1]);
        aZ[0] = MFMA(xa[kx][0], bz, aZ[0]);  aZ[1] = MFMA(xa[kx][1], bz, aZ[1]);
        aNX[0] = MFMA(xa[kx][0], bn, aNX[0]); aNX[1] = MFMA(xa[kx][1], bn, aNX[1]);
      }
    }

    // Epilogue: gates, fp32 carry in regs, publish bf16 h in frag order.
    ushort_t* hAn = hbuf[p ^ 1];
    {
      const int kch = jcB >> 3, sub = jcB & 7;
      ushort_t* base = hAn + kch * 8192 + sub;
#pragma unroll
      for (int mi = 0; mi < 2; ++mi)
#pragma unroll
        for (int v = 0; v < 4; ++v) {
          float r = sigmf(aR[mi][v] + brz);
          float z = sigmf(aZ[mi][v] + bzz);
          float n = tanhf_(aNX[mi][v] + bin + r * (aNH[mi][v] + bhn));
          float h = (1.f - z) * n + z * hreg[mi][v];
          hreg[mi][v] = h;
          int row = m0 + w * 32 + mi * 16 + fq4 * 4 + v;
          base[row * 8] = f2bf(h);
        }
    }
    p ^= 1;
    arrive_wait(&cnt[16 + t * 4 + mt], 64);

    if (t >= 49 && isdec) {
      // out(td) = inp + h_new @ fc^T + fc_b ; publish inp(td+1).
      const int td = t - 49;
      const ushort_t* abase = hbuf[p] + (fq4 * 1024 + rowA) * 8;
      f32x4 fa[2] = {{0.f, 0.f, 0.f, 0.f}, {0.f, 0.f, 0.f, 0.f}};
      bf16x8 a0 = ldg8(abase), a1 = ldg8(abase + 128);
      bf16x8 p0 = ldg8(abase + 32768), p1 = ldg8(abase + 32768 + 128);
#pragma unroll 2
      for (int kt = 0; kt < 32; ++kt) {
        int kp = (kt + 2 < 32) ? kt + 2 : 31;
        bf16x8 n0 = ldg8(abase + kp * 32768);
        bf16x8 n1 = ldg8(abase + kp * 32768 + 128);
        bf16x8 bf = *(const bf16x8*)(fcL + kt * 512 + l * 8);
        fa[0] = MFMA(a0, bf, fa[0]);
        fa[1] = MFMA(a1, bf, fa[1]);
        a0 = p0; a1 = p1; p0 = n0; p1 = n1;
      }
      ushort_t* inn = inbuf[(td + 1) & 1];
      const int kch = jcB >> 3, sub = jcB & 7;
#pragma unroll
      for (int mi = 0; mi < 2; ++mi)
#pragma unroll
        for (int v = 0; v < 4; ++v) {
          int row = m0 + w * 32 + mi * 16 + fq4 * 4 + v;
          float o = fa[mi][v] + inp[mi][v] + fcbr;
          inp[mi][v] = o;
          inn[kch * 8192 + row * 8 + sub] = f2bf(o);
          if (jcB < 55) outp[row * 1375 + td * 55 + jcB] = o;
        }
      __syncthreads();
      if (tid == 0) {
        __threadfence();
        atomicAdd(&cnt[512 + (td + 1) * 4 + mt], 1u);
      }
    }
  }
}

extern "C" void kernel_launch(void* const* d_in, const int* in_sizes, int n_in,
                              void* d_out, int out_size, void* d_ws, size_t ws_size,
                              hipStream_t stream) {
  const float* enc  = (const float*)d_in[0];
  const float* dec  = (const float*)d_in[1];
  const float* Wih  = (const float*)d_in[2];
  const float* Whh  = (const float*)d_in[3];
  const float* b_ih = (const float*)d_in[4];
  const float* b_hh = (const float*)d_in[5];
  const float* fcw  = (const float*)d_in[6];
  const float* fcb  = (const float*)d_in[7];
  float* out = (float*)d_out;

  char* ws = (char*)d_ws;
  unsigned* cnt   = (unsigned*)ws; ws += 4096;
  ushort_t* x_enc = (ushort_t*)ws; ws += (size_t)49 * 65536 * 2;
  ushort_t* hA0   = (ushort_t*)ws; ws += (size_t)1048576 * 2;
  ushort_t* hA1   = (ushort_t*)ws; ws += (size_t)1048576 * 2;
  ushort_t* in0   = (ushort_t*)ws; ws += (size_t)65536 * 2;
  ushort_t* in1   = (ushort_t*)ws; ws += (size_t)65536 * 2;

  hipMemsetAsync(cnt, 0, 4096, stream);
  seq2seq_persist<<<256, 512, 0, stream>>>(
      enc, dec, Wih, Whh, b_ih, b_hh, fcw, fcb, out,
      x_enc, hA0, hA1, in0, in1, cnt);
}

// Round 4
// 3255.099 us; speedup vs baseline: 1.2240x; 1.0118x over previous
//
#include <hip/hip_runtime.h>

// Persistent cooperative seq2seq GRU, round 4.
// 256 blocks x 512 thr (1/CU). mt=b&3 (4 groups of 64, XCD-pair local).
// Master/slave barrier with spread release lines (kills the poll storm).
// Decoder FC distributed over all 64 blocks/group, overlapped with h-GEMM.

typedef unsigned short ushort_t;
typedef __bf16 bf16x8 __attribute__((ext_vector_type(8)));
typedef float f32x4 __attribute__((ext_vector_type(4)));

#define MFMA(a, b, c) __builtin_amdgcn_mfma_f32_16x16x32_bf16(a, b, c, 0, 0, 0)

__device__ __forceinline__ ushort_t f2bf(float f) {
  union { float f; unsigned u; } x; x.f = f;
  unsigned r = x.u + 0x7fffu + ((x.u >> 16) & 1u);
  return (ushort_t)(r >> 16);
}
__device__ __forceinline__ float sigmf(float x) { return 1.f / (1.f + __expf(-x)); }
__device__ __forceinline__ float tanhf_(float x) { return 1.f - 2.f / (__expf(2.f * x) + 1.f); }
__device__ __forceinline__ bf16x8 ldg8(const ushort_t* p) { return *(const bf16x8*)p; }

__global__ __launch_bounds__(512, 2)
void seq2seq_persist(const float* __restrict__ enc, const float* __restrict__ dec,
                     const float* __restrict__ Wih, const float* __restrict__ Whh,
                     const float* __restrict__ b_ih, const float* __restrict__ b_hh,
                     const float* __restrict__ fcw, const float* __restrict__ fcb,
                     float* __restrict__ outp,
                     ushort_t* __restrict__ x_enc,
                     ushort_t* __restrict__ hA0, ushort_t* __restrict__ hA1,
                     ushort_t* __restrict__ inn,
                     unsigned* cnt) {
  // LDS in MFMA-B fragment order [kc][col 16][8] (conflict-free frag reads).
  __shared__ ushort_t WhL[49152];  // 96 KB
  __shared__ ushort_t WiL[3072];   // 6 KB
  __shared__ ushort_t fcL[16384];  // 32 KB

  const int tid = threadIdx.x;
  const int b = blockIdx.x;
  const int mt = b & 3, jt = b >> 2;           // group = 64 blocks, same mt
  const int m0 = mt << 8, j0 = jt << 4;
  const int w = tid >> 6, l = tid & 63;
  const int fr = l & 15, fq4 = l >> 4;
  const int rowA = m0 + w * 32 + fr;
  const int slot = jt & 7;

  unsigned* arr = cnt + mt * 64;                         // 1 line per group
  auto relp = [&](int s) { return cnt + (4 + mt * 8 + s) * 64; };
  auto fcp  = [&](int d) { return cnt + (40 + d * 4 + mt) * 64; };

  // ---------------- init ----------------
  if (jt < 49) {  // x_enc[t=jt][kc][row 1024][8], rows of this mt
    const int t = jt;
    for (int i = tid; i < 2048; i += 512) {
      int kc = i >> 8, row = m0 + (i & 255);
      ushort_t* dst = x_enc + t * 65536 + (kc * 1024 + row) * 8;
      const float* src = enc + (row * 50 + t) * 55 + kc * 8;
#pragma unroll
      for (int j = 0; j < 8; ++j) {
        int k = kc * 8 + j;
        dst[j] = (k < 55) ? f2bf(src[j]) : (ushort_t)0;
      }
    }
  } else if (jt == 49) {  // inn = dec[:,0,:]
    for (int i = tid; i < 2048; i += 512) {
      int kc = i >> 8, row = m0 + (i & 255);
      ushort_t* dst = inn + (kc * 1024 + row) * 8;
      const float* src = dec + row * 1375 + kc * 8;
#pragma unroll
      for (int j = 0; j < 8; ++j) {
        int k = kc * 8 + j;
        dst[j] = (k < 55) ? f2bf(src[j]) : (ushort_t)0;
      }
    }
  }
  for (int i = tid; i < 6144; i += 512) {  // WhL: this block's 16 cols x 3 gates
    int g = i >> 11, c = (i >> 7) & 15, kc = i & 127;
    const float* src = Whh + (size_t)(g * 1024 + j0 + c) * 1024 + kc * 8;
    ushort_t* dst = WhL + ((g * 128 + kc) * 16 + c) * 8;
#pragma unroll
    for (int j = 0; j < 8; ++j) dst[j] = f2bf(src[j]);
  }
  for (int i = tid; i < 384; i += 512) {  // WiL
    int g = i >> 7, c = (i >> 3) & 15, kc = i & 7;
    const float* src = Wih + (size_t)(g * 1024 + j0 + c) * 55 + kc * 8;
    ushort_t* dst = WiL + ((g * 8 + kc) * 16 + c) * 8;
#pragma unroll
    for (int j = 0; j < 8; ++j) {
      int k = kc * 8 + j;
      dst[j] = (k < 55) ? f2bf(src[j]) : (ushort_t)0;
    }
  }
  const int rT = jt & 15, cT = jt >> 4;   // FC tile: rows m0+rT*16, cols cT*16
  for (int i = tid; i < 2048; i += 512) {  // fcL: cols cT*16..+16
    int kc = i >> 4, c = i & 15;
    int col = cT * 16 + c;
    ushort_t* dst = fcL + (kc * 16 + c) * 8;
    const float* src = fcw + (size_t)col * 1024 + kc * 8;
#pragma unroll
    for (int j = 0; j < 8; ++j) dst[j] = (col < 55) ? f2bf(src[j]) : (ushort_t)0;
  }

  // Per-thread constants.
  const int jcB = j0 + fr;
  const float brz = b_ih[jcB] + b_hh[jcB];
  const float bzz = b_ih[1024 + jcB] + b_hh[1024 + jcB];
  const float bin = b_ih[2048 + jcB];
  const float bhn = b_hh[2048 + jcB];
  const int rB = m0 + rT * 16 + fq4 * 4;   // FC row base (+v)
  const int cF = cT * 16 + fr;             // FC col
  const float fcbF = (cF < 55) ? fcb[cF] : 0.f;
  float inp[4];
#pragma unroll
  for (int v = 0; v < 4; ++v)
    inp[v] = (cF < 55) ? dec[(rB + v) * 1375 + cF] : 0.f;
  float hreg[2][4] = {{0.f, 0.f, 0.f, 0.f}, {0.f, 0.f, 0.f, 0.f}};

  // ---------------- barrier helpers ----------------
  auto arrive = [&](unsigned k) {
    __syncthreads();  // all block stores in L2 (waitcnt before s_barrier)
    if (tid == 0) {
      __threadfence();  // write back dirty L2 -> L3
      if (jt == 0) {
        while (__hip_atomic_load(arr, __ATOMIC_RELAXED, __HIP_MEMORY_SCOPE_AGENT) <
               63u * k)
          __builtin_amdgcn_s_sleep(1);
        __builtin_amdgcn_fence(__ATOMIC_RELEASE, "agent");
#pragma unroll
        for (int s = 0; s < 8; ++s)
          __hip_atomic_store(relp(s), k, __ATOMIC_RELAXED, __HIP_MEMORY_SCOPE_AGENT);
      } else {
        atomicAdd(arr, 1u);
      }
    }
  };
  auto wait_rel = [&](unsigned k) {
    __syncthreads();
    if (tid == 0) {
      while (__hip_atomic_load(relp(slot), __ATOMIC_RELAXED, __HIP_MEMORY_SCOPE_AGENT) < k)
        __builtin_amdgcn_s_sleep(4);
    }
    __syncthreads();
    __builtin_amdgcn_fence(__ATOMIC_ACQUIRE, "agent");
  };
  auto fc_arrive = [&](int d) {
    __syncthreads();
    if (tid == 0) { __threadfence(); atomicAdd(fcp(d), 1u); }
  };
  auto fc_wait = [&](int d) {
    __syncthreads();
    if (tid == 0) {
      while (__hip_atomic_load(fcp(d), __ATOMIC_RELAXED, __HIP_MEMORY_SCOPE_AGENT) < 64u)
        __builtin_amdgcn_s_sleep(1);
    }
    __syncthreads();
    __builtin_amdgcn_fence(__ATOMIC_ACQUIRE, "agent");
  };

  ushort_t* hbuf[2] = {hA0, hA1};

  // FC chunk: fa = h[rows rB..] @ fcL, out = fa + inp + fcb; publish inn if td<24.
  auto fcdo = [&](const ushort_t* hb, int td) {
    const ushort_t* ab = hb + (fq4 * 1024 + m0 + rT * 16 + fr) * 8;
    f32x4 fa = (f32x4){0.f, 0.f, 0.f, 0.f};
    bf16x8 F0[4];
#pragma unroll
    for (int i = 0; i < 4; ++i) F0[i] = ldg8(ab + i * 32768);
#pragma unroll
    for (int kt = 0; kt < 32; ++kt) {
      bf16x8 a = F0[kt & 3];
      if (kt < 28) F0[kt & 3] = ldg8(ab + (kt + 4) * 32768);
      bf16x8 bf = *(const bf16x8*)(fcL + kt * 512 + l * 8);
      fa = MFMA(a, bf, fa);
    }
    const int kch = cF >> 3, sub = cF & 7;
#pragma unroll
    for (int v = 0; v < 4; ++v) {
      float o = fa[v] + inp[v] + fcbF;
      inp[v] = o;
      int row = rB + v;
      if (td < 24) inn[kch * 8192 + row * 8 + sub] = f2bf(o);
      if (cF < 55) outp[row * 1375 + td * 55 + cF] = o;
    }
  };

  arrive(1);     // publish init
  wait_rel(1);

  for (int t = 0; t < 74; ++t) {
    f32x4 aR[2], aZ[2], aNH[2], aNX[2];
#pragma unroll
    for (int mi = 0; mi < 2; ++mi) {
      aR[mi] = (f32x4){0.f, 0.f, 0.f, 0.f};
      aZ[mi] = (f32x4){0.f, 0.f, 0.f, 0.f};
      aNH[mi] = (f32x4){0.f, 0.f, 0.f, 0.f};
      aNX[mi] = (f32x4){0.f, 0.f, 0.f, 0.f};
    }

    auto xpart = [&](const ushort_t* Xs) {
      const ushort_t* xb = Xs + (fq4 * 1024 + rowA) * 8;
      bf16x8 xa[2][2];
      xa[0][0] = ldg8(xb);          xa[0][1] = ldg8(xb + 128);
      xa[1][0] = ldg8(xb + 32768);  xa[1][1] = ldg8(xb + 32768 + 128);
#pragma unroll
      for (int kx = 0; kx < 2; ++kx) {
        const ushort_t* bp = WiL + kx * 512 + l * 8;
        bf16x8 br = *(const bf16x8*)(bp);
        bf16x8 bz = *(const bf16x8*)(bp + 1024);
        bf16x8 bn = *(const bf16x8*)(bp + 2048);
        aR[0] = MFMA(xa[kx][0], br, aR[0]);  aR[1] = MFMA(xa[kx][1], br, aR[1]);
        aZ[0] = MFMA(xa[kx][0], bz, aZ[0]);  aZ[1] = MFMA(xa[kx][1], bz, aZ[1]);
        aNX[0] = MFMA(xa[kx][0], bn, aNX[0]); aNX[1] = MFMA(xa[kx][1], bn, aNX[1]);
      }
    };

    if (t <= 48) xpart(x_enc + t * 65536);   // no h dependency -> pre-barrier
    else if (t == 49) xpart(inn);            // init-published dec[:,0]

    if (t > 0) wait_rel(t + 1);              // h(t) visible group-wide

    if (t >= 50) { fcdo(hbuf[t & 1], t - 50); fc_arrive(t - 50); }

    if (t > 0) {  // h-part: 32 kt, depth-4 A prefetch, full unroll
      const ushort_t* ab = hbuf[t & 1] + (fq4 * 1024 + rowA) * 8;
      bf16x8 A0[4], A1[4];
#pragma unroll
      for (int i = 0; i < 4; ++i) {
        A0[i] = ldg8(ab + i * 32768);
        A1[i] = ldg8(ab + i * 32768 + 128);
      }
#pragma unroll
      for (int kt = 0; kt < 32; ++kt) {
        bf16x8 a0 = A0[kt & 3], a1 = A1[kt & 3];
        if (kt < 28) {
          A0[kt & 3] = ldg8(ab + (kt + 4) * 32768);
          A1[kt & 3] = ldg8(ab + (kt + 4) * 32768 + 128);
        }
        const ushort_t* bp = WhL + kt * 512 + l * 8;
        bf16x8 br = *(const bf16x8*)(bp);
        bf16x8 bz = *(const bf16x8*)(bp + 16384);
        bf16x8 bn = *(const bf16x8*)(bp + 32768);
        aR[0] = MFMA(a0, br, aR[0]);   aR[1] = MFMA(a1, br, aR[1]);
        aZ[0] = MFMA(a0, bz, aZ[0]);   aZ[1] = MFMA(a1, bz, aZ[1]);
        aNH[0] = MFMA(a0, bn, aNH[0]); aNH[1] = MFMA(a1, bn, aNH[1]);
      }
    }

    if (t >= 50) { fc_wait(t - 50); xpart(inn); }  // wait overlapped by h-part

    // Epilogue: gates, fp32 carry, publish bf16 h(t+1).
    {
      ushort_t* hAn = hbuf[(t + 1) & 1];
      const int kch = jcB >> 3, sub = jcB & 7;
      ushort_t* base = hAn + kch * 8192 + sub;
#pragma unroll
      for (int mi = 0; mi < 2; ++mi)
#pragma unroll
        for (int v = 0; v < 4; ++v) {
          float r = sigmf(aR[mi][v] + brz);
          float z = sigmf(aZ[mi][v] + bzz);
          float n = tanhf_(aNX[mi][v] + bin + r * (aNH[mi][v] + bhn));
          float h = (1.f - z) * n + z * hreg[mi][v];
          hreg[mi][v] = h;
          int row = m0 + w * 32 + mi * 16 + fq4 * 4 + v;
          base[row * 8] = f2bf(h);
        }
    }
    arrive(t + 2);
  }

  wait_rel(75);
  fcdo(hbuf[0], 24);  // h(74) in hbuf[0]
}

extern "C" void kernel_launch(void* const* d_in, const int* in_sizes, int n_in,
                              void* d_out, int out_size, void* d_ws, size_t ws_size,
                              hipStream_t stream) {
  const float* enc  = (const float*)d_in[0];
  const float* dec  = (const float*)d_in[1];
  const float* Wih  = (const float*)d_in[2];
  const float* Whh  = (const float*)d_in[3];
  const float* b_ih = (const float*)d_in[4];
  const float* b_hh = (const float*)d_in[5];
  const float* fcw  = (const float*)d_in[6];
  const float* fcb  = (const float*)d_in[7];
  float* out = (float*)d_out;

  char* ws = (char*)d_ws;
  unsigned* cnt   = (unsigned*)ws; ws += 65536;
  ushort_t* x_enc = (ushort_t*)ws; ws += (size_t)49 * 65536 * 2;
  ushort_t* hA0   = (ushort_t*)ws; ws += (size_t)1048576 * 2;
  ushort_t* hA1   = (ushort_t*)ws; ws += (size_t)1048576 * 2;
  ushort_t* inn   = (ushort_t*)ws; ws += (size_t)65536 * 2;

  hipMemsetAsync(cnt, 0, 65536, stream);
  seq2seq_persist<<<256, 512, 0, stream>>>(
      enc, dec, Wih, Whh, b_ih, b_hh, fcw, fcb, out,
      x_enc, hA0, hA1, inn, cnt);
}

// Round 6
// 1037.302 us; speedup vs baseline: 3.8409x; 3.1380x over previous
//
#include <hip/hip_runtime.h>

// Round 6 (= round 5 design, compile-fixed): XCD-local persistent GRU.
// 8 groups (= physical XCDs via HW_REG_XCC_ID) x 32 blocks x 512 thr. Group
// owns 128 batch rows; block owns 32 h-cols (x3 gates). h exchange stays in
// one XCD's L2: no wbl2/inv; readers use sc0 (vL1-bypass) buffer loads.
// Whh r/z + Wih in LDS (frag order), n-gate Whh + fc block-private global.
// Waves K-split 2x512 + LDS pair reduction. Decoder FC 8 blocks/group.

typedef unsigned short ushort_t;
typedef __bf16 bf16x8 __attribute__((ext_vector_type(8)));
typedef float f32x4 __attribute__((ext_vector_type(4)));
typedef unsigned int u32x4 __attribute__((ext_vector_type(4)));

#define MFMA(a, b, c) __builtin_amdgcn_mfma_f32_16x16x32_bf16(a, b, c, 0, 0, 0)

static __device__ __forceinline__ ushort_t f2bf(float f) {
  union { float f; unsigned u; } x; x.f = f;
  unsigned r = x.u + 0x7fffu + ((x.u >> 16) & 1u);
  return (ushort_t)(r >> 16);
}
static __device__ __forceinline__ float sigmf(float x) { return 1.f / (1.f + __expf(-x)); }
static __device__ __forceinline__ float tanhf_(float x) { return 1.f - 2.f / (__expf(2.f * x) + 1.f); }

static __device__ __forceinline__ __amdgpu_buffer_rsrc_t mkrsrc(const void* p) {
  return __builtin_amdgcn_make_buffer_rsrc(const_cast<void*>(p), (short)0, -1, 0x00020000);
}
// aux=1 -> sc0: load bypasses vL1, served from (XCD-local) L2.
#if __has_builtin(__builtin_amdgcn_raw_buffer_load_b128)
static __device__ __forceinline__ bf16x8 ldb(__amdgpu_buffer_rsrc_t r, int voff) {
  u32x4 v = __builtin_amdgcn_raw_buffer_load_b128(r, voff, 0, 1);
  union { u32x4 u; bf16x8 b; } x; x.u = v; return x.b;
}
#else
static __device__ __forceinline__ bf16x8 ldb(__amdgpu_buffer_rsrc_t r, int voff) {
  union { unsigned u[4]; bf16x8 b; } x;
  x.u[0] = __builtin_amdgcn_raw_buffer_load_b32(r, voff, 0, 1);
  x.u[1] = __builtin_amdgcn_raw_buffer_load_b32(r, voff + 4, 0, 1);
  x.u[2] = __builtin_amdgcn_raw_buffer_load_b32(r, voff + 8, 0, 1);
  x.u[3] = __builtin_amdgcn_raw_buffer_load_b32(r, voff + 12, 0, 1);
  return x.b;
}
#endif

__global__ __launch_bounds__(512, 2)
void seq2seq_xcd(const float* __restrict__ enc, const float* __restrict__ dec,
                 const float* __restrict__ Wih, const float* __restrict__ Whh,
                 const float* __restrict__ b_ih, const float* __restrict__ b_hh,
                 const float* __restrict__ fcw, const float* __restrict__ fcb,
                 float* __restrict__ outp,
                 ushort_t* __restrict__ xg, ushort_t* __restrict__ hA,
                 ushort_t* __restrict__ innA, ushort_t* __restrict__ nG,
                 ushort_t* __restrict__ fcG, unsigned* cnt) {
  __shared__ ushort_t WrzL[65536];  // [kt32][gate2][jf2][512]  128 KB
  __shared__ ushort_t WiL[6144];    // [kt2][gate3][jf2][512]    12 KB
  __shared__ float scratchF[4096];  // reduction: 4 waves x 64 x 16f  16 KB
  __shared__ unsigned sgs;

  const int tid = threadIdx.x;
  const int w = tid >> 6, l = tid & 63;
  const int fr = l & 15, fq4 = l >> 4;

  // ---- claim XCD-local slot ----
  if (tid == 0) {
    unsigned x;
    asm volatile("s_getreg_b32 %0, hwreg(HW_REG_XCC_ID, 0, 8)" : "=s"(x));
    x &= 7u;
    unsigned s = atomicAdd(&cnt[x * 64], 1u);
    sgs = (x << 8) | s;
  }
  __syncthreads();
  const int g = sgs >> 8, slot = sgs & 255;
  const bool isFC = (slot >= 24);

  unsigned* arrp = cnt + (8 + g) * 64;
  unsigned* relp = cnt + (16 + g * 4 + (slot & 3)) * 64;
  unsigned* relw = cnt + (16 + g * 4) * 64;  // master writes 4 lines (stride 64)
  auto fcpp = [&](int td) { return cnt + (48 + g * 25 + td) * 64; };

  ushort_t* hbase = hA + (size_t)g * 262144;
  auto hb = [&](int i) { return hbase + (size_t)i * 131072; };
  ushort_t* xgg = xg + (size_t)g * 49 * 8192;
  auto inng = [&](int i) { return innA + (size_t)(g * 2 + i) * 8192; };
  ushort_t* nGp = nG + (size_t)(g * 32 + slot) * 32768;
  ushort_t* fcGg = fcG + (size_t)g * 65536;

  // ---- init conversions (all group-local) ----
  for (int i = tid; i < 65536; i += 512) {  // WrzL
    int j = i & 7, ln = (i >> 3) & 63, jf = (i >> 9) & 1, gt = (i >> 10) & 1, kt = i >> 11;
    int col = gt * 1024 + slot * 32 + jf * 16 + (ln & 15);
    int k = kt * 32 + (ln >> 4) * 8 + j;
    WrzL[i] = f2bf(Whh[(size_t)col * 1024 + k]);
  }
  for (int i = tid; i < 6144; i += 512) {  // WiL (r,z,n)
    int j = i & 7, ln = (i >> 3) & 63, jf = (i >> 9) & 1, rem = i >> 10;
    int gt = rem % 3, kt = rem / 3;
    int col = gt * 1024 + slot * 32 + jf * 16 + (ln & 15);
    int k = kt * 32 + (ln >> 4) * 8 + j;
    WiL[i] = (k < 55) ? f2bf(Wih[(size_t)col * 55 + k]) : (ushort_t)0;
  }
  for (int i = tid; i < 32768; i += 512) {  // nG (block-private)
    int j = i & 7, ln = (i >> 3) & 63, jf = (i >> 9) & 1, kt = i >> 10;
    int col = 2048 + slot * 32 + jf * 16 + (ln & 15);
    int k = kt * 32 + (ln >> 4) * 8 + j;
    nGp[i] = f2bf(Whh[(size_t)col * 1024 + k]);
  }
#pragma unroll
  for (int rep = 0; rep < 2; ++rep) {  // xg: t = slot, slot+32
    int t = slot + rep * 32;
    if (t < 49) {
      ushort_t* xp = xgg + (size_t)t * 8192;
      for (int i = tid; i < 8192; i += 512) {
        int sub = i & 7, row = (i >> 3) & 127, kc = i >> 10;
        int c = kc * 8 + sub;
        xp[i] = (c < 55) ? f2bf(enc[((size_t)(g * 128 + row) * 50 + t) * 55 + c]) : (ushort_t)0;
      }
    }
  }
  if (slot < 4) {  // inn(0) = dec[:,0,:]
    ushort_t* ip = inng(0);
    for (int i = slot * 2048 + tid; i < (slot + 1) * 2048; i += 512) {
      int sub = i & 7, row = (i >> 3) & 127, kc = i >> 10;
      int c = kc * 8 + sub;
      ip[i] = (c < 55) ? f2bf(dec[(size_t)(g * 128 + row) * 1375 + c]) : (ushort_t)0;
    }
  }
  if (isFC) {  // fcG: group-shared, slot s converts kt 4(s-24)..+3
    for (int i = (slot - 24) * 8192 + tid; i < (slot - 23) * 8192; i += 512) {
      int j = i & 7, ln = (i >> 3) & 63, jf = (i >> 9) & 3, kt = i >> 11;
      int c = jf * 16 + (ln & 15);
      int k = kt * 32 + (ln >> 4) * 8 + j;
      fcGg[i] = (c < 55) ? f2bf(fcw[(size_t)c * 1024 + k]) : (ushort_t)0;
    }
  }

  // ---- per-thread constants ----
  float brz[2], bzz[2], bin[2], bhn[2];
#pragma unroll
  for (int jf = 0; jf < 2; ++jf) {
    int col = slot * 32 + jf * 16 + fr;
    brz[jf] = b_ih[col] + b_hh[col];
    bzz[jf] = b_ih[1024 + col] + b_hh[1024 + col];
    bin[jf] = b_ih[2048 + col];
    bhn[jf] = b_hh[2048 + col];
  }
  const int Rfc = (slot - 24) * 16;      // FC block rows (if isFC)
  const int jfF = w & 3;
  const int colF = jfF * 16 + fr;
  float fcbF = 0.f, inp[4] = {0.f, 0.f, 0.f, 0.f};
  if (isFC && w < 4) {
    fcbF = (colF < 55) ? fcb[colF] : 0.f;
#pragma unroll
    for (int v = 0; v < 4; ++v)
      inp[v] = (colF < 55) ? dec[(size_t)(g * 128 + Rfc + fq4 * 4 + v) * 1375 + colF] : 0.f;
  }
  f32x4 hreg[4];  // waves 0-3: [mi*2+jf]
#pragma unroll
  for (int i = 0; i < 4; ++i) hreg[i] = (f32x4){0.f, 0.f, 0.f, 0.f};

  // ---- barrier (group = one XCD; no cache maintenance) ----
  auto arrive = [&](unsigned k) {
    __syncthreads();  // drains vmcnt: all stores complete at (shared) L2
    if (tid == 0) {
      if (slot == 0) {
        while (__hip_atomic_load(arrp, __ATOMIC_RELAXED, __HIP_MEMORY_SCOPE_AGENT) < 31u * k)
          __builtin_amdgcn_s_sleep(1);
#pragma unroll
        for (int s = 0; s < 4; ++s)
          __hip_atomic_store(relw + s * 64, k, __ATOMIC_RELAXED, __HIP_MEMORY_SCOPE_AGENT);
      } else {
        atomicAdd(arrp, 1u);
      }
    }
  };
  auto wait_rel = [&](unsigned k) {
    __syncthreads();
    if (tid == 0) {
      while (__hip_atomic_load(relp, __ATOMIC_RELAXED, __HIP_MEMORY_SCOPE_AGENT) < k)
        __builtin_amdgcn_s_sleep(1);
    }
    __syncthreads();
  };
  auto fc_arrive = [&](int td) {
    __syncthreads();
    if (tid == 0) atomicAdd(fcpp(td), 1u);
  };
  auto fc_wait = [&](int td) {
    __syncthreads();
    if (tid == 0) {
      while (__hip_atomic_load(fcpp(td), __ATOMIC_RELAXED, __HIP_MEMORY_SCOPE_AGENT) < 8u)
        __builtin_amdgcn_s_sleep(1);
    }
    __syncthreads();
  };

  // ---- accumulators: r/z/nH K-split in av[12]; nX on waves 0-3 ----
  f32x4 av[12], nx[4];

  auto xpart = [&](const ushort_t* xp) {  // waves 0-3 only; full K=64
    __amdgpu_buffer_rsrc_t rx = mkrsrc(xp);
    const int R = w * 32;
#pragma unroll
    for (int kt = 0; kt < 2; ++kt) {
      bf16x8 a0 = ldb(rx, ((kt * 4 + fq4) * 128 + R + fr) * 16);
      bf16x8 a1 = ldb(rx, ((kt * 4 + fq4) * 128 + R + 16 + fr) * 16);
      const ushort_t* bl = WiL + kt * 3072 + l * 8;
#pragma unroll
      for (int jf = 0; jf < 2; ++jf) {
        bf16x8 br = *(const bf16x8*)(bl + jf * 512);
        bf16x8 bz = *(const bf16x8*)(bl + 1024 + jf * 512);
        bf16x8 bn = *(const bf16x8*)(bl + 2048 + jf * 512);
        av[jf] = MFMA(a0, br, av[jf]);
        av[2 + jf] = MFMA(a1, br, av[2 + jf]);
        av[4 + jf] = MFMA(a0, bz, av[4 + jf]);
        av[6 + jf] = MFMA(a1, bz, av[6 + jf]);
        nx[jf] = MFMA(a0, bn, nx[jf]);
        nx[2 + jf] = MFMA(a1, bn, nx[2 + jf]);
      }
    }
  };

  auto hpart = [&](const ushort_t* hbp) {  // all waves; K-split halves
    __amdgpu_buffer_rsrc_t r = mkrsrc(hbp);
    const int kh = w >> 2, R = (w & 3) * 32;
    bf16x8 A0[4], A1[4];
#pragma unroll
    for (int i = 0; i < 4; ++i) {
      int kt = kh * 16 + i;
      A0[i] = ldb(r, ((kt * 4 + fq4) * 128 + R + fr) * 16);
      A1[i] = ldb(r, ((kt * 4 + fq4) * 128 + R + 16 + fr) * 16);
    }
#pragma unroll
    for (int i = 0; i < 16; ++i) {
      int kt = kh * 16 + i;
      bf16x8 a0 = A0[i & 3], a1 = A1[i & 3];
      if (i < 12) {
        int kp = kt + 4;
        A0[i & 3] = ldb(r, ((kp * 4 + fq4) * 128 + R + fr) * 16);
        A1[i & 3] = ldb(r, ((kp * 4 + fq4) * 128 + R + 16 + fr) * 16);
      }
      const ushort_t* bl = WrzL + kt * 2048 + l * 8;
      const ushort_t* np = nGp + kt * 1024 + l * 8;
#pragma unroll
      for (int jf = 0; jf < 2; ++jf) {
        bf16x8 br = *(const bf16x8*)(bl + jf * 512);
        bf16x8 bz = *(const bf16x8*)(bl + 1024 + jf * 512);
        bf16x8 bn = *(const bf16x8*)(np + jf * 512);
        av[jf] = MFMA(a0, br, av[jf]);
        av[2 + jf] = MFMA(a1, br, av[2 + jf]);
        av[4 + jf] = MFMA(a0, bz, av[4 + jf]);
        av[6 + jf] = MFMA(a1, bz, av[6 + jf]);
        av[8 + jf] = MFMA(a0, bn, av[8 + jf]);
        av[10 + jf] = MFMA(a1, bn, av[10 + jf]);
      }
    }
  };

  auto kreduce = [&]() {  // waves 4-7 partials -> waves 0-3 (3 regs x 4 rounds)
#pragma unroll
    for (int rd = 0; rd < 4; ++rd) {
      if (w >= 4) {
        f32x4* sp = (f32x4*)(scratchF + ((w - 4) * 64 + l) * 16);
        sp[0] = av[rd * 3]; sp[1] = av[rd * 3 + 1]; sp[2] = av[rd * 3 + 2];
      }
      __syncthreads();
      if (w < 4) {
        const f32x4* sp = (const f32x4*)(scratchF + (w * 64 + l) * 16);
        av[rd * 3] += sp[0]; av[rd * 3 + 1] += sp[1]; av[rd * 3 + 2] += sp[2];
      }
      __syncthreads();
    }
  };

  auto fcdo = [&](const ushort_t* hbp, int td, bool wr, ushort_t* innW) {
    __amdgpu_buffer_rsrc_t r = mkrsrc(hbp);
    const int kh = w >> 2;
    f32x4 fa = (f32x4){0.f, 0.f, 0.f, 0.f};
    bf16x8 Af[4];
#pragma unroll
    for (int i = 0; i < 4; ++i) {
      int kt = kh * 16 + i;
      Af[i] = ldb(r, ((kt * 4 + fq4) * 128 + Rfc + fr) * 16);
    }
#pragma unroll
    for (int i = 0; i < 16; ++i) {
      int kt = kh * 16 + i;
      bf16x8 a = Af[i & 3];
      if (i < 12) Af[i & 3] = ldb(r, (((kt + 4) * 4 + fq4) * 128 + Rfc + fr) * 16);
      bf16x8 bb = *(const bf16x8*)(fcGg + (kt * 4 + jfF) * 512 + l * 8);
      fa = MFMA(a, bb, fa);
    }
    if (w >= 4) *(f32x4*)(scratchF + ((w - 4) * 64 + l) * 16) = fa;
    __syncthreads();
    if (w < 4) {
      fa += *(const f32x4*)(scratchF + (w * 64 + l) * 16);
      const int kq = colF >> 3, sub = colF & 7;
#pragma unroll
      for (int v = 0; v < 4; ++v) {
        int row = Rfc + fq4 * 4 + v;
        float o = fa[v] + inp[v] + fcbF;
        inp[v] = o;
        if (wr) innW[(kq * 128 + row) * 8 + sub] = f2bf(o);
        if (colF < 55) outp[(size_t)(g * 128 + row) * 1375 + td * 55 + colF] = o;
      }
    }
    __syncthreads();
  };

  arrive(1);
  wait_rel(1);

  for (int t = 0; t < 74; ++t) {
#pragma unroll
    for (int i = 0; i < 12; ++i) av[i] = (f32x4){0.f, 0.f, 0.f, 0.f};
#pragma unroll
    for (int i = 0; i < 4; ++i) nx[i] = (f32x4){0.f, 0.f, 0.f, 0.f};

    if (t <= 49) {
      if (w < 4) xpart(t <= 48 ? xgg + (size_t)t * 8192 : inng(0));
    }
    if (t > 0) wait_rel(t + 1);
    if (t >= 50 && isFC) {
      fcdo(hb(t & 1), t - 50, true, inng((t - 49) & 1));
      fc_arrive(t - 50);
    }
    if (t > 0) hpart(hb(t & 1));
    if (t >= 50) {
      fc_wait(t - 50);
      if (w < 4) xpart(inng((t - 49) & 1));
    }
    kreduce();
    if (w < 4) {  // epilogue: gates + fp32 carry + publish bf16 h(t+1)
      ushort_t* hn = hb((t + 1) & 1);
#pragma unroll
      for (int mi = 0; mi < 2; ++mi)
#pragma unroll
        for (int jf = 0; jf < 2; ++jf) {
          f32x4 R_ = av[mi * 2 + jf], Z_ = av[4 + mi * 2 + jf];
          f32x4 NH = av[8 + mi * 2 + jf], NX = nx[mi * 2 + jf];
          const int kq = slot * 4 + jf * 2 + (fr >> 3), sub = fr & 7;
#pragma unroll
          for (int v = 0; v < 4; ++v) {
            float rr = sigmf(R_[v] + brz[jf]);
            float zz = sigmf(Z_[v] + bzz[jf]);
            float nn = tanhf_(NX[v] + bin[jf] + rr * (NH[v] + bhn[jf]));
            float h = (1.f - zz) * nn + zz * hreg[mi * 2 + jf][v];
            hreg[mi * 2 + jf][v] = h;
            int row = w * 32 + mi * 16 + fq4 * 4 + v;
            hn[(kq * 128 + row) * 8 + sub] = f2bf(h);
          }
        }
    }
    arrive(t + 2);
  }

  if (isFC) {
    wait_rel(75);
    fcdo(hb(0), 24, false, (ushort_t*)0);
  }
}

extern "C" void kernel_launch(void* const* d_in, const int* in_sizes, int n_in,
                              void* d_out, int out_size, void* d_ws, size_t ws_size,
                              hipStream_t stream) {
  const float* enc  = (const float*)d_in[0];
  const float* dec  = (const float*)d_in[1];
  const float* Wih  = (const float*)d_in[2];
  const float* Whh  = (const float*)d_in[3];
  const float* b_ih = (const float*)d_in[4];
  const float* b_hh = (const float*)d_in[5];
  const float* fcw  = (const float*)d_in[6];
  const float* fcb  = (const float*)d_in[7];
  float* out = (float*)d_out;

  char* ws = (char*)d_ws;
  unsigned* cnt  = (unsigned*)ws; ws += 65536;
  ushort_t* xg   = (ushort_t*)ws; ws += (size_t)8 * 49 * 8192 * 2;   // 6.42 MB
  ushort_t* hA   = (ushort_t*)ws; ws += (size_t)8 * 2 * 131072 * 2;  // 4 MB
  ushort_t* innA = (ushort_t*)ws; ws += (size_t)8 * 2 * 8192 * 2;    // 256 KB
  ushort_t* nG   = (ushort_t*)ws; ws += (size_t)8 * 32 * 32768 * 2;  // 16 MB
  ushort_t* fcG  = (ushort_t*)ws; ws += (size_t)8 * 65536 * 2;       // 1 MB

  (void)hipMemsetAsync(cnt, 0, 65536, stream);
  seq2seq_xcd<<<256, 512, 0, stream>>>(
      enc, dec, Wih, Whh, b_ih, b_hh, fcw, fcb, out,
      xg, hA, innA, nG, fcG, cnt);
}